// Round 2
// baseline (37091.254 us; speedup 1.0000x reference)
//
#include <hip/hip_runtime.h>
#include <math.h>

#define T_STEPS 512
#define BATCH   128
#define HDIM    300
#define M       20

// ---------------- JAX threefry2x32 noise replication ----------------
// Replicates jax.random.uniform(jax.random.key(42), (T,B,M), f32, 0.01, 1.0)
// under jax_threefry_partitionable=True (default since JAX 0.4.36):
//   counts1 = hi32(i) = 0, counts2 = lo32(i) = i
//   (b1, b2) = threefry2x32((0,42), (counts1, counts2))
//   bits = b1 ^ b2
//   f = bitcast((bits>>9)|0x3f800000) - 1;  v = f*(1-0.01)+0.01;  max(0.01, v)
__device__ __forceinline__ unsigned rotl32(unsigned v, int r) {
    return (v << r) | (v >> (32 - r));
}

__device__ float jax_noise(unsigned i) {
#pragma clang fp contract(off)
    unsigned x0 = 0u;   // hi word of linear index (always 0: N < 2^32)
    unsigned x1 = i;    // lo word
    const unsigned ks0 = 0u, ks1 = 42u, ks2 = 0u ^ 42u ^ 0x1BD11BDAu;
    x0 += ks0; x1 += ks1;
    // rounds 1-4: rotations {13,15,26,6}
    x0 += x1; x1 = rotl32(x1, 13); x1 ^= x0;
    x0 += x1; x1 = rotl32(x1, 15); x1 ^= x0;
    x0 += x1; x1 = rotl32(x1, 26); x1 ^= x0;
    x0 += x1; x1 = rotl32(x1, 6);  x1 ^= x0;
    x0 += ks1; x1 += ks2 + 1u;
    // rounds 5-8: {17,29,16,24}
    x0 += x1; x1 = rotl32(x1, 17); x1 ^= x0;
    x0 += x1; x1 = rotl32(x1, 29); x1 ^= x0;
    x0 += x1; x1 = rotl32(x1, 16); x1 ^= x0;
    x0 += x1; x1 = rotl32(x1, 24); x1 ^= x0;
    x0 += ks2; x1 += ks0 + 2u;
    // rounds 9-12: {13,15,26,6}
    x0 += x1; x1 = rotl32(x1, 13); x1 ^= x0;
    x0 += x1; x1 = rotl32(x1, 15); x1 ^= x0;
    x0 += x1; x1 = rotl32(x1, 26); x1 ^= x0;
    x0 += x1; x1 = rotl32(x1, 6);  x1 ^= x0;
    x0 += ks0; x1 += ks1 + 3u;
    // rounds 13-16: {17,29,16,24}
    x0 += x1; x1 = rotl32(x1, 17); x1 ^= x0;
    x0 += x1; x1 = rotl32(x1, 29); x1 ^= x0;
    x0 += x1; x1 = rotl32(x1, 16); x1 ^= x0;
    x0 += x1; x1 = rotl32(x1, 24); x1 ^= x0;
    x0 += ks1; x1 += ks2 + 4u;
    // rounds 17-20: {13,15,26,6}
    x0 += x1; x1 = rotl32(x1, 13); x1 ^= x0;
    x0 += x1; x1 = rotl32(x1, 15); x1 ^= x0;
    x0 += x1; x1 = rotl32(x1, 26); x1 ^= x0;
    x0 += x1; x1 = rotl32(x1, 6);  x1 ^= x0;
    x0 += ks2; x1 += ks0 + 5u;

    const unsigned bits = x0 ^ x1;   // partitionable mode: xor of both words
    const unsigned fb = (bits >> 9) | 0x3f800000u;
    float f = __uint_as_float(fb) - 1.0f;        // [0,1)
    const float span = 1.0f - 0.01f;
    float v = f * span;
    v = v + 0.01f;
    return fmaxf(0.01f, v);
}

// ---------------- main persistent per-batch kernel ----------------
// grid = 128 blocks (one per batch element), 640 threads = 10 waves.
// waves 0-4 ("lower"): sim-path columns; waves 5-9 ("upper"): cand-path columns.
__global__ void __launch_bounds__(640)
wm_kernel(const float* __restrict__ hs,   // (T,B,H)
          const float* __restrict__ msk,  // (T,B)
          const float* __restrict__ We1,  // (300,300)
          const float* __restrict__ be1,  // (300)
          const float* __restrict__ We2,  // (300,1)
          const float* __restrict__ be2,  // (1)
          const float* __restrict__ Ws1,  // (901,300)
          const float* __restrict__ bs1,  // (300)
          const float* __restrict__ Ws2,  // (300,1)
          const float* __restrict__ bs2,  // (1)
          const float* __restrict__ Wu,   // (600,300)
          const float* __restrict__ bu,   // (300)
          float* __restrict__ out)
{
    __shared__ __align__(16) float sh_mem[M][HDIM];
    __shared__ __align__(16) float sh_h[HDIM];
    __shared__ float sh_hb1[HDIM];
    __shared__ float sh_hwua[HDIM];
    __shared__ float sh_usage[M];
    __shared__ float sh_simpart[5][M];
    __shared__ float sh_entpart[5];
    __shared__ float sh_ow[M];
    __shared__ float sh_indv[M];

    const int b    = blockIdx.x;
    const int tid  = threadIdx.x;
    const bool lower = tid < 320;
    const int c    = lower ? tid : (tid - 320);
    const bool act_c = c < HDIM;
    const int wave = tid >> 6;   // 0..9
    const int lane = tid & 63;

    // ---- init state ----
    for (int idx = tid; idx < M * HDIM; idx += 640) ((float*)sh_mem)[idx] = 0.0f;
    if (tid < M) sh_usage[tid] = 0.0f;

    const float be2v = be2[0];
    const float bs2v = bs2[0];
    // step-invariant per-column scalars
    float bs1c = 0.f, be1c = 0.f, we2c = 0.f, ws2c = 0.f, w3c = 0.f, buc = 0.f;
    if (act_c) {
        if (lower) {
            bs1c = bs1[c]; be1c = be1[c]; we2c = We2[c];
            ws2c = Ws2[c]; w3c = Ws1[900 * 300 + c];
        } else {
            buc = bu[c];
        }
    }
    __syncthreads();

    for (int t = 0; t < T_STEPS; ++t) {
        const int tb = t * BATCH + b;

        // ---- load h (upper half) ----
        if (!lower && act_c) sh_h[c] = hs[(size_t)tb * HDIM + c];
        __syncthreads();

        // ---- Phase A: h-GEMVs (hb1 = h@Ws1b + bs1, hwua = h@WuA + bu, ent partials) ----
        float a1 = 0.f, ae = 0.f, au = 0.f;
        if (act_c) {
            if (lower) {
                const float* pB = Ws1 + 90000 + c;   // rows 300..599
                const float* pE = We1 + c;
                for (int k = 0; k < HDIM; k += 4) {
                    float4 h4 = *(const float4*)&sh_h[k];
                    const float* q  = pB + k * 300;
                    const float* qe = pE + k * 300;
                    a1 += h4.x * q[0] + h4.y * q[300] + h4.z * q[600] + h4.w * q[900];
                    ae += h4.x * qe[0] + h4.y * qe[300] + h4.z * qe[600] + h4.w * qe[900];
                }
            } else {
                const float* pU = Wu + c;            // rows 0..299
                for (int k = 0; k < HDIM; k += 4) {
                    float4 h4 = *(const float4*)&sh_h[k];
                    const float* q = pU + k * 300;
                    au += h4.x * q[0] + h4.y * q[300] + h4.z * q[600] + h4.w * q[900];
                }
            }
        }
        if (lower) {
            float er = act_c ? (fmaxf(ae + be1c, 0.0f) * we2c) : 0.0f;
            for (int off = 32; off; off >>= 1) er += __shfl_xor(er, off, 64);
            if (lane == 0) sh_entpart[wave] = er;
            if (act_c) sh_hb1[c] = a1 + bs1c;
        } else {
            if (act_c) sh_hwua[c] = au + buc;
        }
        __syncthreads();

        // ---- Phase B: big K-loops ----
        float acc[M];
        if (lower) {
            const float hb1c = act_c ? sh_hb1[c] : 0.0f;
            const float w3 = act_c ? w3c : 0.0f;
#pragma unroll
            for (int j = 0; j < M; ++j) acc[j] = hb1c + sh_usage[j] * w3;
            if (act_c) {
                const float* pA = Ws1 + c;            // rows 0..299  (mem)
                const float* pC = Ws1 + 180000 + c;   // rows 600..899 (h*mem)
                for (int k = 0; k < HDIM; k += 4) {
                    float4 h4 = *(const float4*)&sh_h[k];
                    const float* qa = pA + k * 300;
                    const float* qc = pC + k * 300;
                    float w0 = fmaf(h4.x, qc[0],   qa[0]);
                    float w1 = fmaf(h4.y, qc[300], qa[300]);
                    float w2 = fmaf(h4.z, qc[600], qa[600]);
                    float w3r = fmaf(h4.w, qc[900], qa[900]);
#pragma unroll
                    for (int j = 0; j < M; ++j) {
                        float4 mv = *(const float4*)&sh_mem[j][k];
                        acc[j] += mv.x * w0 + mv.y * w1 + mv.z * w2 + mv.w * w3r;
                    }
                }
            }
            // relu * Ws2, reduce over columns -> sim partials
            const float w2c = act_c ? ws2c : 0.0f;
#pragma unroll
            for (int j = 0; j < M; ++j) {
                float v = fmaxf(acc[j], 0.0f) * w2c;
                for (int off = 32; off; off >>= 1) v += __shfl_xor(v, off, 64);
                if (lane == 0) sh_simpart[wave][j] = v;
            }
        } else {
            const float hwc = act_c ? sh_hwua[c] : 0.0f;
#pragma unroll
            for (int j = 0; j < M; ++j) acc[j] = hwc;
            if (act_c) {
                const float* pU = Wu + 90000 + c;     // rows 300..599 (mem)
                for (int k = 0; k < HDIM; k += 4) {
                    const float* q = pU + k * 300;
                    float u0 = q[0], u1 = q[300], u2 = q[600], u3 = q[900];
#pragma unroll
                    for (int j = 0; j < M; ++j) {
                        float4 mv = *(const float4*)&sh_mem[j][k];
                        acc[j] += mv.x * u0 + mv.y * u1 + mv.z * u2 + mv.w * u3;
                    }
                }
            }
#pragma unroll
            for (int j = 0; j < M; ++j) acc[j] = tanhf(acc[j]);  // cand
        }
        __syncthreads();

        // ---- Phase C: decision (wave 0) ----
        if (wave == 0) {
            const bool act = lane < M;
            float simj = -INFINITY, usg = 0.0f;
            if (act) {
                float s = sh_simpart[0][lane];
                s += sh_simpart[1][lane];
                s += sh_simpart[2][lane];
                s += sh_simpart[3][lane];
                s += sh_simpart[4][lane];
                simj = s + bs2v;
                usg = sh_usage[lane];
            }
            float es = sh_entpart[0] + sh_entpart[1] + sh_entpart[2]
                     + sh_entpart[3] + sh_entpart[4] + be2v;
            const float entp = (1.0f / (1.0f + expf(-es))) * msk[tb];

            const float coref = (act && usg > 0.0f) ? 1.0f : 0.0f;
            float comb = act ? ((usg > 0.0f) ? simj : -10000.0f) : -INFINITY;
            float mx = comb;
            for (int off = 32; off; off >>= 1) mx = fmaxf(mx, __shfl_xor(mx, off, 64));
            mx = fmaxf(mx, 0.0f);
            float e = act ? expf(comb - mx) : 0.0f;
            const float eM = expf(0.0f - mx);
            float den = e;
            for (int off = 32; off; off >>= 1) den += __shfl_xor(den, off, 64);
            den += eM;
            const float prob  = e / den;
            const float probM = eM / den;
            float masked = prob * coref;
            float msum = masked;
            for (int off = 32; off; off >>= 1) msum += __shfl_xor(msum, off, 64);
            msum += probM;
            const float dn = msum + 1e-8f;
            const float normj = masked / dn;
            const float normM = probM / dn;
            const float indv = act ? (entp * normj) : 0.0f;
            const float ow_base = entp * normM;

            // nsim = softmax(sim)
            float nmx = simj;
            for (int off = 32; off; off >>= 1) nmx = fmaxf(nmx, __shfl_xor(nmx, off, 64));
            float ne = act ? expf(simj - nmx) : 0.0f;
            float ns = ne;
            for (int off = 32; off; off >>= 1) ns += __shfl_xor(ns, off, 64);
            const float nsim = ne / ns;

            float ows = act ? (((usg == 0.0f) ? nsim * 100000.0f : 0.0f) + (1.0f - usg))
                            : -INFINITY;
            float mv = ows;
            for (int off = 32; off; off >>= 1) mv = fmaxf(mv, __shfl_xor(mv, off, 64));

            float key = 0.0f;
            if (act && ows == mv) key = jax_noise((unsigned)(tb * M + lane));
            float bv = act ? key : -1.0f;
            int bi = act ? lane : 1023;
            for (int off = 32; off; off >>= 1) {
                float ov = __shfl_xor(bv, off, 64);
                int oi = __shfl_xor(bi, off, 64);
                if (ov > bv || (ov == bv && oi < bi)) { bv = ov; bi = oi; }
            }
            const float ow = (act && lane == bi) ? ow_base : 0.0f;
            const float nu = fminf(1.0f, (ow + indv) + 0.98f * usg);

            if (act) {
                sh_ow[lane] = ow;
                sh_indv[lane] = indv;
                sh_usage[lane] = nu;
                const int base = tb * M + lane;
                out[65536 + base]   = nu;                                   // usage_seq
                out[1376256 + base] = indv * (1.0f - 1e-8f) + 1e-8f;        // coref
                out[2686976 + base] = ow * (1.0f - 1e-8f) + 1e-8f;          // overwrite
            }
            if (lane == 0) out[tb] = entp * (1.0f - 1e-8f) + 1e-8f;          // ent
        }
        __syncthreads();

        // ---- Phase D: memory update (upper half; acc holds tanh'd cand) ----
        if (!lower && act_c) {
            const float hc = sh_h[c];
#pragma unroll
            for (int j = 0; j < M; ++j) {
                const float owj = sh_ow[j];
                const float inj = sh_indv[j];
                const float mo = sh_mem[j][c];
                sh_mem[j][c] = owj * hc + (1.0f - owj - inj) * mo + inj * acc[j];
            }
        }
        __syncthreads();
    }
}

extern "C" void kernel_launch(void* const* d_in, const int* in_sizes, int n_in,
                              void* d_out, int out_size, void* d_ws, size_t ws_size,
                              hipStream_t stream) {
    (void)in_sizes; (void)n_in; (void)d_ws; (void)ws_size; (void)out_size;
    const float* hs  = (const float*)d_in[0];
    const float* msk = (const float*)d_in[1];
    const float* We1 = (const float*)d_in[2];
    const float* be1 = (const float*)d_in[3];
    const float* We2 = (const float*)d_in[4];
    const float* be2 = (const float*)d_in[5];
    const float* Ws1 = (const float*)d_in[6];
    const float* bs1 = (const float*)d_in[7];
    const float* Ws2 = (const float*)d_in[8];
    const float* bs2 = (const float*)d_in[9];
    const float* Wu  = (const float*)d_in[10];
    const float* bu  = (const float*)d_in[11];
    float* out = (float*)d_out;

    hipLaunchKernelGGL(wm_kernel, dim3(BATCH), dim3(640), 0, stream,
                       hs, msk, We1, be1, We2, be2, Ws1, bs1, Ws2, bs2, Wu, bu, out);
}